// Round 6
// baseline (285.388 us; speedup 1.0000x reference)
//
#include <hip/hip_runtime.h>

// Chamfer via MFMA — R18: 256-VGPR budget to kill AGPR round-trips.
// R17 probe findings: loop = 7.6 µs/rep, VALUBusy 63% >> fold-math floor
// (~20%), VGPR_Count=52 -> the 1024-thr block's 128-VGPR cap pushed MFMA
// C/D + accumulators into AGPRs; folds round-trip via v_accvgpr movs
// (~2/3 of loop VALU). Non-loop section ~16 µs (mystery, deferred).
// R18: 512-thr blocks (8 waves, __launch_bounds__(512,2) -> 256 VGPR) so
// EVERYTHING stays in VGPRs; each wave owns 4 col-tiles (live ~160 VGPR):
// pure v_min3 folds, 8 MFMAs per A-pair ds_read (2x LDS reuse).
// Grid stays 256=(batch,dir); LDS 64 KB; 1 block/CU; 2 waves/SIMD.
// BITWISE SAFETY: wave wv writes TWO partials -- tiles{0,1} ->
// part[blk*16+2wv], tiles{2,3} -> part[blk*16+2wv+1] -- with fold order,
// 16->1 tree, shfl_xor, sqrt order, shfl_down tree all IDENTICAL to old
// waves 2wv/2wv+1 => part[] bitwise identical, final kernel unchanged,
// absmax 0.0 preserved.
// (Packing PROVEN R6-R12: A k {psqh,psql,-2ph|-2pl...}, B k {1,1,qh|ql...};
//  d2 = psq+qsq-2p.q in one v_mfma_f32_32x32x16_bf16 per 32x32 tile.)

typedef short bf16x8 __attribute__((ext_vector_type(8)));
typedef float f32x16 __attribute__((ext_vector_type(16)));

#define ONE_BF 0x3f80

__device__ __forceinline__ unsigned short f2bf(float x) {
    unsigned u = __float_as_uint(x);
    u += 0x7fffu + ((u >> 16) & 1u);          // round-to-nearest-even
    return (unsigned short)(u >> 16);
}
__device__ __forceinline__ float bf2f(unsigned short h) {
    return __uint_as_float(((unsigned)h) << 16);
}

__global__ __launch_bounds__(512, 2) void chamfer_dir(
    const float4* __restrict__ P, const float4* __restrict__ Q,
    float* __restrict__ part)
{
    __shared__ short lAh[1024 * 8];   // A k-slots 0-7  (16 KB)
    __shared__ short lAl[1024 * 8];   // A k-slots 8-15 (16 KB)
    __shared__ short lB[1024 * 16];   // B interleaved [pt][half][8] (32 KB)
    // total 64 KB; 8 waves/block, 1 block/CU, 2 waves/SIMD -> 256 VGPR.

    const int blk   = blockIdx.x;      // 0..255
    const int batch = blk >> 1;        // 0..127
    const int dir   = blk & 1;         // 0: rows=P cols=Q; 1: swapped
    const int t     = threadIdx.x;     // 0..511
    const int base  = batch << 10;

    const float4* __restrict__ ownb = (dir ? Q : P) + base;   // rows
    const float4* __restrict__ oppb = (dir ? P : Q) + base;   // cols

    // ---- Pack rows into LDS A-fragments: 2 pts/thread ----
#pragma unroll
    for (int i = 0; i < 2; ++i) {
        const int pt = t + (i << 9);
        float4 v = ownb[pt];
        float psq = v.y * v.y + v.z * v.z + v.w * v.w;
        unsigned short psqh = f2bf(psq);
        unsigned short psql = f2bf(psq - bf2f(psqh));
        unsigned short yh = f2bf(v.y), zh = f2bf(v.z), wh = f2bf(v.w);
        unsigned short m2yh = f2bf(-2.0f * bf2f(yh));
        unsigned short m2zh = f2bf(-2.0f * bf2f(zh));
        unsigned short m2wh = f2bf(-2.0f * bf2f(wh));
        unsigned short m2yl = f2bf(-2.0f * (v.y - bf2f(yh)));
        unsigned short m2zl = f2bf(-2.0f * (v.z - bf2f(zh)));
        unsigned short m2wl = f2bf(-2.0f * (v.w - bf2f(wh)));
        bf16x8 ah = { (short)psqh, (short)psql, (short)m2yh, (short)m2zh,
                      (short)m2wh, (short)m2yl, (short)m2zl, (short)m2wl };
        bf16x8 al = { (short)m2yh, (short)m2zh, (short)m2wh,
                      (short)ONE_BF, (short)ONE_BF, 0, 0, 0 };
        *(bf16x8*)&lAh[pt * 8] = ah;
        *(bf16x8*)&lAl[pt * 8] = al;
    }
    // ---- Pack ALL 1024 cols into LDS B-fragments: 2 pts/thread ----
#pragma unroll
    for (int i = 0; i < 2; ++i) {
        const int pt = t + (i << 9);
        float4 v = oppb[pt];
        float qsq = v.y * v.y + v.z * v.z + v.w * v.w;
        unsigned short qsqh = f2bf(qsq);
        unsigned short qsql = f2bf(qsq - bf2f(qsqh));
        unsigned short yh = f2bf(v.y), zh = f2bf(v.z), wh = f2bf(v.w);
        unsigned short yl = f2bf(v.y - bf2f(yh));
        unsigned short zl = f2bf(v.z - bf2f(zh));
        unsigned short wl = f2bf(v.w - bf2f(wh));
        bf16x8 bh = { (short)ONE_BF, (short)ONE_BF, (short)yh, (short)zh,
                      (short)wh, (short)yh, (short)zh, (short)wh };
        bf16x8 bl = { (short)yl, (short)zl, (short)wl,
                      (short)qsqh, (short)qsql, 0, 0, 0 };
        *(bf16x8*)&lB[pt * 16]     = bh;
        *(bf16x8*)&lB[pt * 16 + 8] = bl;
    }
    __syncthreads();

    const int lane = t & 63;
    const int half = lane >> 5;    // k-half: 0 -> slots 0-7, 1 -> 8-15
    const int l31  = lane & 31;
    const int wv   = t >> 6;       // 0..7

    // Byte-addressed A base; all loop offsets are compile-time immediates.
    const char* __restrict__ aB =
        (const char*)(half ? lAl : lAh) + l31 * 16;

    // FOUR col-tiles per wave: c0 = wv*4 .. wv*4+3  (cols 128wv..128wv+127)
    const int c0 = wv << 2;
    bf16x8 bf0 = *(const bf16x8*)&lB[((((c0)     << 5) + l31) * 2 + half) * 8];
    bf16x8 bf1 = *(const bf16x8*)&lB[((((c0 + 1) << 5) + l31) * 2 + half) * 8];
    bf16x8 bf2 = *(const bf16x8*)&lB[((((c0 + 2) << 5) + l31) * 2 + half) * 8];
    bf16x8 bf3 = *(const bf16x8*)&lB[((((c0 + 3) << 5) + l31) * 2 + half) * 8];

    f32x16 zf;
#pragma unroll
    for (int j = 0; j < 16; ++j) zf[j] = 0.0f;

    f32x16 acc0, acc1, acc2, acc3;

    // Prologue: load row-tile pair 0 into set A (1-deep SSA prefetch, R16).
    bf16x8 afA0 = *(const bf16x8*)(aB);
    bf16x8 afA1 = *(const bf16x8*)(aB + 512);
    bf16x8 afB0 = afA0, afB1 = afA1;   // dead init

#pragma unroll
    for (int i = 0; i < 16; ++i) {
        bf16x8 f0, f1;
        if ((i & 1) == 0) { f0 = afA0; f1 = afA1; }
        else              { f0 = afB0; f1 = afB1; }
        // Prefetch pair i+1 into the OTHER set before this pair's MFMAs.
        if (i < 15) {
            if ((i & 1) == 0) {
                afB0 = *(const bf16x8*)(aB + ((i + 1) << 10));
                afB1 = *(const bf16x8*)(aB + ((i + 1) << 10) + 512);
            } else {
                afA0 = *(const bf16x8*)(aB + ((i + 1) << 10));
                afA1 = *(const bf16x8*)(aB + ((i + 1) << 10) + 512);
            }
        }
        // Tile 0 (fold order identical to old wave 2wv, acc0)
        {
            f32x16 ca = __builtin_amdgcn_mfma_f32_32x32x16_bf16(f0, bf0, zf, 0, 0, 0);
            f32x16 cb = __builtin_amdgcn_mfma_f32_32x32x16_bf16(f1, bf0, zf, 0, 0, 0);
            if (i == 0) {
#pragma unroll
                for (int j = 0; j < 16; ++j) acc0[j] = fminf(ca[j], cb[j]);
            } else {
#pragma unroll
                for (int j = 0; j < 16; ++j)
                    acc0[j] = fminf(fminf(ca[j], cb[j]), acc0[j]);   // v_min3
            }
        }
        // Tile 1 (old wave 2wv, acc1)
        {
            f32x16 ca = __builtin_amdgcn_mfma_f32_32x32x16_bf16(f0, bf1, zf, 0, 0, 0);
            f32x16 cb = __builtin_amdgcn_mfma_f32_32x32x16_bf16(f1, bf1, zf, 0, 0, 0);
            if (i == 0) {
#pragma unroll
                for (int j = 0; j < 16; ++j) acc1[j] = fminf(ca[j], cb[j]);
            } else {
#pragma unroll
                for (int j = 0; j < 16; ++j)
                    acc1[j] = fminf(fminf(ca[j], cb[j]), acc1[j]);
            }
        }
        // Tile 2 (old wave 2wv+1, acc0)
        {
            f32x16 ca = __builtin_amdgcn_mfma_f32_32x32x16_bf16(f0, bf2, zf, 0, 0, 0);
            f32x16 cb = __builtin_amdgcn_mfma_f32_32x32x16_bf16(f1, bf2, zf, 0, 0, 0);
            if (i == 0) {
#pragma unroll
                for (int j = 0; j < 16; ++j) acc2[j] = fminf(ca[j], cb[j]);
            } else {
#pragma unroll
                for (int j = 0; j < 16; ++j)
                    acc2[j] = fminf(fminf(ca[j], cb[j]), acc2[j]);
            }
        }
        // Tile 3 (old wave 2wv+1, acc1)
        {
            f32x16 ca = __builtin_amdgcn_mfma_f32_32x32x16_bf16(f0, bf3, zf, 0, 0, 0);
            f32x16 cb = __builtin_amdgcn_mfma_f32_32x32x16_bf16(f1, bf3, zf, 0, 0, 0);
            if (i == 0) {
#pragma unroll
                for (int j = 0; j < 16; ++j) acc3[j] = fminf(ca[j], cb[j]);
            } else {
#pragma unroll
                for (int j = 0; j < 16; ++j)
                    acc3[j] = fminf(fminf(ca[j], cb[j]), acc3[j]);
            }
        }
    }

    // ---- Epilogue A: tiles {0,1} == old wave 2wv (identical order) ----
    {
        float m0 = acc0[0], m1 = acc1[0];
#pragma unroll
        for (int j = 1; j < 16; ++j) { m0 = fminf(m0, acc0[j]); m1 = fminf(m1, acc1[j]); }
        m0 = fminf(m0, __shfl_xor(m0, 32, 64));
        m1 = fminf(m1, __shfl_xor(m1, 32, 64));
        float s = 0.0f;
        if (half == 0)
            s = sqrtf(fmaxf(m0, 0.0f) + 1e-12f) + sqrtf(fmaxf(m1, 0.0f) + 1e-12f);
#pragma unroll
        for (int off = 32; off; off >>= 1) s += __shfl_down(s, off, 64);
        if (lane == 0) part[(blk << 4) + (wv << 1)] = s;
    }
    // ---- Epilogue B: tiles {2,3} == old wave 2wv+1 (identical order) ----
    {
        float m0 = acc2[0], m1 = acc3[0];
#pragma unroll
        for (int j = 1; j < 16; ++j) { m0 = fminf(m0, acc2[j]); m1 = fminf(m1, acc3[j]); }
        m0 = fminf(m0, __shfl_xor(m0, 32, 64));
        m1 = fminf(m1, __shfl_xor(m1, 32, 64));
        float s = 0.0f;
        if (half == 0)
            s = sqrtf(fmaxf(m0, 0.0f) + 1e-12f) + sqrtf(fmaxf(m1, 0.0f) + 1e-12f);
#pragma unroll
        for (int off = 32; off; off >>= 1) s += __shfl_down(s, off, 64);
        if (lane == 0) part[(blk << 4) + (wv << 1) + 1] = s;
    }
}

__global__ __launch_bounds__(256) void chamfer_final(
    const float* __restrict__ part, float* __restrict__ out)
{
    __shared__ float ws[4];
    const int t = threadIdx.x;
    // Same linear 4096-partial array + same summation order as R14/R16.
    float s = 0.0f;
#pragma unroll
    for (int k = 0; k < 4; ++k) {
        const float4 w = *(const float4*)&part[(t + (k << 8)) << 2];
        float bk = ((w.x + w.y) + w.z) + w.w;
        s = (k == 0) ? bk : (s + bk);
    }
#pragma unroll
    for (int off = 32; off; off >>= 1) s += __shfl_down(s, off, 64);
    if ((t & 63) == 0) ws[t >> 6] = s;
    __syncthreads();
    if (t == 0) out[0] = ws[0] + ws[1] + ws[2] + ws[3];
}

extern "C" void kernel_launch(void* const* d_in, const int* in_sizes, int n_in,
                              void* d_out, int out_size, void* d_ws, size_t ws_size,
                              hipStream_t stream) {
    const float4* P = (const float4*)d_in[0];
    const float4* Q = (const float4*)d_in[1];
    float* out  = (float*)d_out;
    float* part = (float*)d_ws;   // 4096 per-wave partials (16 KB)

    chamfer_dir<<<dim3(128 * 2), dim3(512), 0, stream>>>(P, Q, part);
    chamfer_final<<<dim3(1), dim3(256), 0, stream>>>(part, out);
}

// Round 7
// 66.513 us; speedup vs baseline: 4.2907x; 4.2907x over previous
//
#include <hip/hip_runtime.h>

// Chamfer via MFMA — R19: 2-waves/SIMD (256-reg budget) WITHOUT R18's
// register blow-up: each wave runs its 4 col-tiles as TWO SEQUENTIAL
// 2-tile phases (phase p == exact R16 body of old wave 2wv+p).
// R18 post-mortem: VGPR_Count=128 + 559MB WRITE = arch/acc 128/128 split,
// 4 concurrent f32x16 accs overflowed the arch half -> scratch spill.
// R17 probe: R16 loop = 7.6 µs/rep, ~2/3 of it v_accvgpr round-trips
// (52-VGPR cap at 4 waves/SIMD); non-loop ~16 µs.
// R19 live set per phase ~130 arch VGPR (acc 32 + transients 32 + zf 16 +
// A-frags 32 + B 8 + addr) -> fits, no AGPRs, no spill. LDS reads, MFMA
// count, fold ops all IDENTICAL to R16 (65.5 µs).
// BITWISE SAFETY: phase p of wave wv reproduces old wave w=2wv+p exactly:
// col-tiles {4wv+2p, 4wv+2p+1}, same fold order, same epilogue tree,
// same part[blk*16+2wv+p] slot -> part[] bitwise identical, final kernel
// unchanged, absmax 0.0 preserved.
// (Packing PROVEN R6-R12: A k {psqh,psql,-2ph|-2pl...}, B k {1,1,qh|ql...};
//  d2 = psq+qsq-2p.q in one v_mfma_f32_32x32x16_bf16 per 32x32 tile.)

typedef short bf16x8 __attribute__((ext_vector_type(8)));
typedef float f32x16 __attribute__((ext_vector_type(16)));

#define ONE_BF 0x3f80

__device__ __forceinline__ unsigned short f2bf(float x) {
    unsigned u = __float_as_uint(x);
    u += 0x7fffu + ((u >> 16) & 1u);          // round-to-nearest-even
    return (unsigned short)(u >> 16);
}
__device__ __forceinline__ float bf2f(unsigned short h) {
    return __uint_as_float(((unsigned)h) << 16);
}

__global__ __launch_bounds__(512, 2) void chamfer_dir(
    const float4* __restrict__ P, const float4* __restrict__ Q,
    float* __restrict__ part)
{
    __shared__ short lAh[1024 * 8];   // A k-slots 0-7  (16 KB)
    __shared__ short lAl[1024 * 8];   // A k-slots 8-15 (16 KB)
    __shared__ short lB[1024 * 16];   // B interleaved [pt][half][8] (32 KB)
    // 64 KB; 8 waves/block, 1 block/CU, 2 waves/SIMD -> 256-reg budget.

    const int blk   = blockIdx.x;      // 0..255
    const int batch = blk >> 1;        // 0..127
    const int dir   = blk & 1;         // 0: rows=P cols=Q; 1: swapped
    const int t     = threadIdx.x;     // 0..511
    const int base  = batch << 10;

    const float4* __restrict__ ownb = (dir ? Q : P) + base;   // rows
    const float4* __restrict__ oppb = (dir ? P : Q) + base;   // cols

    // ---- Pack rows into LDS A-fragments: 2 pts/thread ----
#pragma unroll
    for (int i = 0; i < 2; ++i) {
        const int pt = t + (i << 9);
        float4 v = ownb[pt];
        float psq = v.y * v.y + v.z * v.z + v.w * v.w;
        unsigned short psqh = f2bf(psq);
        unsigned short psql = f2bf(psq - bf2f(psqh));
        unsigned short yh = f2bf(v.y), zh = f2bf(v.z), wh = f2bf(v.w);
        unsigned short m2yh = f2bf(-2.0f * bf2f(yh));
        unsigned short m2zh = f2bf(-2.0f * bf2f(zh));
        unsigned short m2wh = f2bf(-2.0f * bf2f(wh));
        unsigned short m2yl = f2bf(-2.0f * (v.y - bf2f(yh)));
        unsigned short m2zl = f2bf(-2.0f * (v.z - bf2f(zh)));
        unsigned short m2wl = f2bf(-2.0f * (v.w - bf2f(wh)));
        bf16x8 ah = { (short)psqh, (short)psql, (short)m2yh, (short)m2zh,
                      (short)m2wh, (short)m2yl, (short)m2zl, (short)m2wl };
        bf16x8 al = { (short)m2yh, (short)m2zh, (short)m2wh,
                      (short)ONE_BF, (short)ONE_BF, 0, 0, 0 };
        *(bf16x8*)&lAh[pt * 8] = ah;
        *(bf16x8*)&lAl[pt * 8] = al;
    }
    // ---- Pack ALL 1024 cols into LDS B-fragments: 2 pts/thread ----
#pragma unroll
    for (int i = 0; i < 2; ++i) {
        const int pt = t + (i << 9);
        float4 v = oppb[pt];
        float qsq = v.y * v.y + v.z * v.z + v.w * v.w;
        unsigned short qsqh = f2bf(qsq);
        unsigned short qsql = f2bf(qsq - bf2f(qsqh));
        unsigned short yh = f2bf(v.y), zh = f2bf(v.z), wh = f2bf(v.w);
        unsigned short yl = f2bf(v.y - bf2f(yh));
        unsigned short zl = f2bf(v.z - bf2f(zh));
        unsigned short wl = f2bf(v.w - bf2f(wh));
        bf16x8 bh = { (short)ONE_BF, (short)ONE_BF, (short)yh, (short)zh,
                      (short)wh, (short)yh, (short)zh, (short)wh };
        bf16x8 bl = { (short)yl, (short)zl, (short)wl,
                      (short)qsqh, (short)qsql, 0, 0, 0 };
        *(bf16x8*)&lB[pt * 16]     = bh;
        *(bf16x8*)&lB[pt * 16 + 8] = bl;
    }
    __syncthreads();

    const int lane = t & 63;
    const int half = lane >> 5;    // k-half: 0 -> slots 0-7, 1 -> 8-15
    const int l31  = lane & 31;
    const int wv   = t >> 6;       // 0..7

    // Byte-addressed A base; loop offsets are compile-time immediates.
    const char* __restrict__ aB =
        (const char*)(half ? lAl : lAh) + l31 * 16;

    // Two sequential phases; phase p == old R16 wave 2wv+p.
#pragma unroll
    for (int p = 0; p < 2; ++p) {
        const int c0 = (wv << 2) + (p << 1);   // col-tiles c0, c0+1
        bf16x8 bf0 = *(const bf16x8*)&lB[((((c0)     << 5) + l31) * 2 + half) * 8];
        bf16x8 bf1 = *(const bf16x8*)&lB[((((c0 + 1) << 5) + l31) * 2 + half) * 8];

        f32x16 zf;
#pragma unroll
        for (int j = 0; j < 16; ++j) zf[j] = 0.0f;

        f32x16 acc0, acc1;

        // Prologue: load row-tile pair 0 into set A (1-deep SSA prefetch).
        bf16x8 afA0 = *(const bf16x8*)(aB);
        bf16x8 afA1 = *(const bf16x8*)(aB + 512);
        bf16x8 afB0 = afA0, afB1 = afA1;   // dead init

#pragma unroll
        for (int i = 0; i < 16; ++i) {
            bf16x8 f0, f1;
            if ((i & 1) == 0) { f0 = afA0; f1 = afA1; }
            else              { f0 = afB0; f1 = afB1; }
            // Prefetch pair i+1 into the OTHER set before this pair's MFMAs.
            if (i < 15) {
                if ((i & 1) == 0) {
                    afB0 = *(const bf16x8*)(aB + ((i + 1) << 10));
                    afB1 = *(const bf16x8*)(aB + ((i + 1) << 10) + 512);
                } else {
                    afA0 = *(const bf16x8*)(aB + ((i + 1) << 10));
                    afA1 = *(const bf16x8*)(aB + ((i + 1) << 10) + 512);
                }
            }
            f32x16 ca = __builtin_amdgcn_mfma_f32_32x32x16_bf16(f0, bf0, zf, 0, 0, 0);
            f32x16 cb = __builtin_amdgcn_mfma_f32_32x32x16_bf16(f1, bf0, zf, 0, 0, 0);
            if (i == 0) {
#pragma unroll
                for (int j = 0; j < 16; ++j) acc0[j] = fminf(ca[j], cb[j]);
            } else {
#pragma unroll
                for (int j = 0; j < 16; ++j)
                    acc0[j] = fminf(fminf(ca[j], cb[j]), acc0[j]);   // v_min3
            }
            f32x16 cc = __builtin_amdgcn_mfma_f32_32x32x16_bf16(f0, bf1, zf, 0, 0, 0);
            f32x16 cd = __builtin_amdgcn_mfma_f32_32x32x16_bf16(f1, bf1, zf, 0, 0, 0);
            if (i == 0) {
#pragma unroll
                for (int j = 0; j < 16; ++j) acc1[j] = fminf(cc[j], cd[j]);
            } else {
#pragma unroll
                for (int j = 0; j < 16; ++j)
                    acc1[j] = fminf(fminf(cc[j], cd[j]), acc1[j]);
            }
        }

        // Epilogue (identical arithmetic + order to R16).
        float m0 = acc0[0], m1 = acc1[0];
#pragma unroll
        for (int j = 1; j < 16; ++j) { m0 = fminf(m0, acc0[j]); m1 = fminf(m1, acc1[j]); }
        m0 = fminf(m0, __shfl_xor(m0, 32, 64));
        m1 = fminf(m1, __shfl_xor(m1, 32, 64));

        float s = 0.0f;
        if (half == 0)
            s = sqrtf(fmaxf(m0, 0.0f) + 1e-12f) + sqrtf(fmaxf(m1, 0.0f) + 1e-12f);
#pragma unroll
        for (int off = 32; off; off >>= 1) s += __shfl_down(s, off, 64);
        if (lane == 0) part[(blk << 4) + (wv << 1) + p] = s;
    }
}

__global__ __launch_bounds__(256) void chamfer_final(
    const float* __restrict__ part, float* __restrict__ out)
{
    __shared__ float ws[4];
    const int t = threadIdx.x;
    // Same linear 4096-partial array + same summation order as R14/R16.
    float s = 0.0f;
#pragma unroll
    for (int k = 0; k < 4; ++k) {
        const float4 w = *(const float4*)&part[(t + (k << 8)) << 2];
        float bk = ((w.x + w.y) + w.z) + w.w;
        s = (k == 0) ? bk : (s + bk);
    }
#pragma unroll
    for (int off = 32; off; off >>= 1) s += __shfl_down(s, off, 64);
    if ((t & 63) == 0) ws[t >> 6] = s;
    __syncthreads();
    if (t == 0) out[0] = ws[0] + ws[1] + ws[2] + ws[3];
}

extern "C" void kernel_launch(void* const* d_in, const int* in_sizes, int n_in,
                              void* d_out, int out_size, void* d_ws, size_t ws_size,
                              hipStream_t stream) {
    const float4* P = (const float4*)d_in[0];
    const float4* Q = (const float4*)d_in[1];
    float* out  = (float*)d_out;
    float* part = (float*)d_ws;   // 4096 per-wave partials (16 KB)

    chamfer_dir<<<dim3(128 * 2), dim3(512), 0, stream>>>(P, Q, part);
    chamfer_final<<<dim3(1), dim3(256), 0, stream>>>(part, out);
}